// Round 4
// baseline (104.787 us; speedup 1.0000x reference)
//
#include <hip/hip_runtime.h>

#define G 64
#define C 32
#define D 18432
#define KSUB 128        // cols per LDS subtile
#define PSTR 136        // padded bf16 row stride (272 B -> <=2-way banking, free)
#define PLANE (32 * PSTR)
#define EPS 1e-5f
#define NS_ITERS 5

typedef __attribute__((ext_vector_type(8))) short short8v;
typedef __attribute__((ext_vector_type(4))) float float4v;

__device__ __forceinline__ void split3(float x, unsigned short& h1,
                                       unsigned short& h2, unsigned short& h3) {
    unsigned int u = __float_as_uint(x);
    unsigned int m1 = u & 0xffff0000u;
    float r1 = x - __uint_as_float(m1);
    unsigned int u2 = __float_as_uint(r1);
    unsigned int m2 = u2 & 0xffff0000u;
    float r2 = r1 - __uint_as_float(m2);
    h1 = (unsigned short)(m1 >> 16);
    h2 = (unsigned short)(m2 >> 16);
    h3 = (unsigned short)(__float_as_uint(r2) >> 16);
}

// ---------------------------------------------------------------------------
// K1: per (group, chunk): partial Gram P = Z_chunk * Z_chunk^T via bf16 MFMA
//     (3-term split, fp32-grade), partial row sums. Prefetch-pipelined.
//     grid = (NCHT, G), block = 256
// ---------------------------------------------------------------------------
template <int NCHT>
__global__ __launch_bounds__(256) void k1_gram(const float* __restrict__ W,
                                               float* __restrict__ psum,
                                               float* __restrict__ prow) {
    constexpr int TD  = D / NCHT;
    constexpr int NST = TD / KSUB;

    __shared__ __align__(16) unsigned short lds_u[3 * PLANE];   // 26112 B

    const int ch   = blockIdx.x;
    const int g    = blockIdx.y;
    const int bid  = g * NCHT + ch;
    const int tid  = threadIdx.x;
    const int lane = tid & 63;
    const int wave = tid >> 6;
    const float* Zg = W + (size_t)g * C * D + (size_t)ch * TD;

    // staging: thread owns row r, 16 cols starting at cb (per subtile)
    const int r  = tid >> 3;            // 0..31
    const int cb = (tid & 7) * 16;      // 0,16,...,112
    const float* srcRow = Zg + (size_t)r * D;

    // compute: fragment geometry for mfma_f32_16x16x32_bf16
    const int lh = lane & 15;
    const int kb = (lane >> 4) * 8;
    const int kbase = wave * 32;

    float4v acc[2][2];
#pragma unroll
    for (int a = 0; a < 2; ++a)
#pragma unroll
        for (int b = 0; b < 2; ++b) acc[a][b] = (float4v)0.f;
    float rs = 0.f;

    float4 cur[4], nxt[4];
#pragma unroll
    for (int i = 0; i < 4; ++i)
        cur[i] = *(const float4*)(srcRow + cb + 4 * i);

#pragma unroll
    for (int st = 0; st < NST; ++st) {
        // prefetch next subtile EARLY — latency hides under split+MFMA
        if (st + 1 < NST) {
            const float* s = srcRow + (st + 1) * KSUB + cb;
#pragma unroll
            for (int i = 0; i < 4; ++i) nxt[i] = *(const float4*)(s + 4 * i);
        }
        // ---- split cur -> 3 bf16 planes in LDS ----
        float x[16];
#pragma unroll
        for (int i = 0; i < 4; ++i) {
            x[4 * i + 0] = cur[i].x; x[4 * i + 1] = cur[i].y;
            x[4 * i + 2] = cur[i].z; x[4 * i + 3] = cur[i].w;
        }
        unsigned short h1[16], h2[16], h3[16];
#pragma unroll
        for (int i = 0; i < 16; ++i) {
            rs += x[i];
            split3(x[i], h1[i], h2[i], h3[i]);
        }
        if (st) __syncthreads();   // prior compute finished reading LDS
        const int widx = r * PSTR + cb;
#pragma unroll
        for (int q = 0; q < 2; ++q) {
            short8v v1, v2, v3;
#pragma unroll
            for (int j = 0; j < 8; ++j) {
                v1[j] = (short)h1[8 * q + j];
                v2[j] = (short)h2[8 * q + j];
                v3[j] = (short)h3[8 * q + j];
            }
            *(short8v*)&lds_u[widx + 8 * q]             = v1;
            *(short8v*)&lds_u[PLANE + widx + 8 * q]     = v2;
            *(short8v*)&lds_u[2 * PLANE + widx + 8 * q] = v3;
        }
        __syncthreads();
        // ---- 6 fragment reads, 24 MFMAs ----
        short8v fr[2][3];
#pragma unroll
        for (int h = 0; h < 2; ++h)
#pragma unroll
            for (int p = 0; p < 3; ++p)
                fr[h][p] = *(const short8v*)&lds_u[p * PLANE + (16 * h + lh) * PSTR + kbase + kb];
#pragma unroll
        for (int a = 0; a < 2; ++a)
#pragma unroll
            for (int b = 0; b < 2; ++b) {
                float4v t = acc[a][b];
                t = __builtin_amdgcn_mfma_f32_16x16x32_bf16(fr[a][0], fr[b][0], t, 0, 0, 0);
                t = __builtin_amdgcn_mfma_f32_16x16x32_bf16(fr[a][0], fr[b][1], t, 0, 0, 0);
                t = __builtin_amdgcn_mfma_f32_16x16x32_bf16(fr[a][1], fr[b][0], t, 0, 0, 0);
                t = __builtin_amdgcn_mfma_f32_16x16x32_bf16(fr[a][1], fr[b][1], t, 0, 0, 0);
                t = __builtin_amdgcn_mfma_f32_16x16x32_bf16(fr[a][0], fr[b][2], t, 0, 0, 0);
                t = __builtin_amdgcn_mfma_f32_16x16x32_bf16(fr[a][2], fr[b][0], t, 0, 0, 0);
                acc[a][b] = t;
            }
#pragma unroll
        for (int i = 0; i < 4; ++i) cur[i] = nxt[i];
    }

    // ---- rowsum: 8 consecutive lanes share a row ----
#pragma unroll
    for (int off = 1; off <= 4; off <<= 1) rs += __shfl_xor(rs, off, 64);
    if ((tid & 7) == 0) prow[(size_t)bid * C + r] = rs;

    // ---- cross-wave Gram reduction (reuse LDS as red[4][32][33] f32) ----
    __syncthreads();
    float* red = (float*)lds_u;
#pragma unroll
    for (int a = 0; a < 2; ++a)
#pragma unroll
        for (int b = 0; b < 2; ++b)
#pragma unroll
            for (int j = 0; j < 4; ++j) {
                int row = 16 * a + ((lane >> 4) << 2) + j;   // m89-verified C/D map
                int col = 16 * b + lh;
                red[wave * 1056 + row * 33 + col] = acc[a][b][j];
            }
    __syncthreads();
#pragma unroll
    for (int k = 0; k < 4; ++k) {
        int el = tid + 256 * k;
        int row = el >> 5, col = el & 31;
        int o = row * 33 + col;
        float sv = red[o] + red[1056 + o] + red[2112 + o] + red[3168 + o];
        psum[(size_t)bid * (C * C) + el] = sv;
    }
}

// ---------------------------------------------------------------------------
// K2: per group: S = sum(partials) - D*m*m^T + EPS*I; Frobenius-normalize;
//     5 Newton-Schulz iterations; emit M^T and v = M*m.
// ---------------------------------------------------------------------------
template <int NCHT>
__global__ __launch_bounds__(256) void k2_ns(const float* __restrict__ psum,
                                             const float* __restrict__ prow,
                                             float* __restrict__ MT,
                                             float* __restrict__ vout) {
    __shared__ float S[C][C + 1];
    __shared__ float B[C][C + 1];
    __shared__ float T1[C][C + 1];
    __shared__ float T2[C][C + 1];
    __shared__ float mean[C];
    __shared__ float redw[4];
    __shared__ float normsh;

    const int g   = blockIdx.x;
    const int tid = threadIdx.x;
    const int e   = tid & 31;
    const int cbq = tid >> 5;

    float selt[4];
#pragma unroll
    for (int k = 0; k < 4; ++k) {
        int el = tid + 256 * k;
        float s = 0.f;
#pragma unroll
        for (int ch = 0; ch < NCHT; ++ch)
            s += psum[((size_t)g * NCHT + ch) * (C * C) + el];
        selt[k] = s;
    }
    if (tid < C) {
        float s = 0.f;
#pragma unroll
        for (int ch = 0; ch < NCHT; ++ch)
            s += prow[((size_t)g * NCHT + ch) * C + tid];
        mean[tid] = s / (float)D;
    }
    __syncthreads();

    float ss = 0.f;
#pragma unroll
    for (int k = 0; k < 4; ++k) {
        int el = tid + 256 * k;
        int c = el >> 5;
        float sv = selt[k] - (float)D * mean[c] * mean[e];
        if (c == e) sv += EPS;
        S[c][e] = sv;
        ss = fmaf(sv, sv, ss);
    }
#pragma unroll
    for (int off = 32; off >= 1; off >>= 1) ss += __shfl_xor(ss, off, 64);
    if ((tid & 63) == 0) redw[tid >> 6] = ss;
    __syncthreads();
    if (tid == 0) normsh = sqrtf(redw[0] + redw[1] + redw[2] + redw[3]);
    __syncthreads();
    const float inv_norm = 1.0f / normsh;
#pragma unroll
    for (int k = 0; k < 4; ++k) {
        int c = cbq + 8 * k;
        S[c][e] *= inv_norm;
        B[c][e] = (c == e) ? 1.f : 0.f;
    }
    __syncthreads();

    for (int it = 0; it < NS_ITERS; ++it) {
#pragma unroll
        for (int k = 0; k < 4; ++k) {
            int c = cbq + 8 * k;
            float s = 0.f;
            for (int kk = 0; kk < C; ++kk)
                s = fmaf(B[c][kk], B[kk][e], s);
            T1[c][e] = s;
        }
        __syncthreads();
#pragma unroll
        for (int k = 0; k < 4; ++k) {
            int c = cbq + 8 * k;
            float s = 0.f;
            for (int kk = 0; kk < C; ++kk)
                s = fmaf(T1[c][kk], B[kk][e], s);
            T2[c][e] = s;
        }
        __syncthreads();
        float pv[4];
#pragma unroll
        for (int k = 0; k < 4; ++k) {
            int c = cbq + 8 * k;
            float s = 0.f;
            for (int kk = 0; kk < C; ++kk)
                s = fmaf(T2[c][kk], S[kk][e], s);
            pv[k] = s;
        }
#pragma unroll
        for (int k = 0; k < 4; ++k) {
            int c = cbq + 8 * k;
            B[c][e] = 1.5f * B[c][e] - 0.5f * pv[k];
        }
        __syncthreads();
    }

    const float invs = 1.0f / sqrtf(normsh);
#pragma unroll
    for (int k = 0; k < 4; ++k) {
        int c = cbq + 8 * k;
        MT[(size_t)g * (C * C) + e * C + c] = B[c][e] * invs;
    }
    if (tid < C) {
        float s = 0.f;
        for (int ee = 0; ee < C; ++ee)
            s = fmaf(B[tid][ee] * invs, mean[ee], s);
        vout[(size_t)g * C + tid] = s;
    }
}

// ---------------------------------------------------------------------------
// K3: W_out = M * Z - v * 1^T, 2 cols/thread; NON-TEMPORAL stores so W stays
//     resident in L3 for the re-read.  grid = (36, 64), block = 256
// ---------------------------------------------------------------------------
__global__ __launch_bounds__(256) void k3_apply(const float* __restrict__ W,
                                                const float* __restrict__ MT,
                                                const float* __restrict__ vv,
                                                float* __restrict__ out) {
    const int g  = blockIdx.y;
    const int d0 = blockIdx.x * 512 + (int)threadIdx.x * 2;
    const float* Zg = W + (size_t)g * C * D + d0;
    const float* Mg = MT + (size_t)g * (C * C);

    float accx[C], accy[C];
#pragma unroll
    for (int r = 0; r < C; ++r) { accx[r] = 0.f; accy[r] = 0.f; }

    for (int e = 0; e < C; ++e) {
        float2 z = *(const float2*)(Zg + (size_t)e * D);
#pragma unroll
        for (int r = 0; r < C; ++r) {
            float m = Mg[e * C + r];   // wave-uniform -> scalar load
            accx[r] = fmaf(m, z.x, accx[r]);
            accy[r] = fmaf(m, z.y, accy[r]);
        }
    }

    float* Og = out + (size_t)g * C * D + d0;
#pragma unroll
    for (int r = 0; r < C; ++r) {
        float vr = vv[g * C + r];      // wave-uniform
        float2 o = make_float2(accx[r] - vr, accy[r] - vr);
        double dv;
        __builtin_memcpy(&dv, &o, 8);
        __builtin_nontemporal_store(dv, (double*)(Og + (size_t)r * D));
    }
}

extern "C" void kernel_launch(void* const* d_in, const int* in_sizes, int n_in,
                              void* d_out, int out_size, void* d_ws, size_t ws_size,
                              hipStream_t stream) {
    const float* w = (const float*)d_in[0];
    float* out = (float*)d_out;

    const size_t need36 = ((size_t)G * 36 * (C * C + C) + (size_t)G * (C * C + C)) * sizeof(float);
    const bool use36 = (ws_size >= need36);
    const int nch = use36 ? 36 : 16;

    float* psum = (float*)d_ws;
    float* prow = psum + (size_t)(G * nch) * (C * C);
    float* MT   = prow + (size_t)(G * nch) * C;
    float* vv   = MT   + (size_t)G * (C * C);

    if (use36) {
        k1_gram<36><<<dim3(36, G), 256, 0, stream>>>(w, psum, prow);
        k2_ns<36>  <<<G,           256, 0, stream>>>(psum, prow, MT, vv);
    } else {
        k1_gram<16><<<dim3(16, G), 256, 0, stream>>>(w, psum, prow);
        k2_ns<16>  <<<G,           256, 0, stream>>>(psum, prow, MT, vv);
    }
    k3_apply<<<dim3(D / 512, G), 256, 0, stream>>>(w, MT, vv, out);
}

// Round 5
// 103.417 us; speedup vs baseline: 1.0132x; 1.0132x over previous
//
#include <hip/hip_runtime.h>

#define G 64
#define C 32
#define D 18432
#define KSUB 128        // cols per LDS subtile
#define PSTR 136        // padded bf16 row stride (272 B -> <=2-way banking, free)
#define PLANE (32 * PSTR)
#define EPS 1e-5f
#define NS_ITERS 5

typedef __attribute__((ext_vector_type(8))) short short8v;
typedef __attribute__((ext_vector_type(4))) float float4v;

__device__ __forceinline__ void split3(float x, unsigned short& h1,
                                       unsigned short& h2, unsigned short& h3) {
    unsigned int u = __float_as_uint(x);
    unsigned int m1 = u & 0xffff0000u;
    float r1 = x - __uint_as_float(m1);
    unsigned int u2 = __float_as_uint(r1);
    unsigned int m2 = u2 & 0xffff0000u;
    float r2 = r1 - __uint_as_float(m2);
    h1 = (unsigned short)(m1 >> 16);
    h2 = (unsigned short)(m2 >> 16);
    h3 = (unsigned short)(__float_as_uint(r2) >> 16);
}

// ---------------------------------------------------------------------------
// K1: per (group, chunk): partial Gram P = Z_chunk * Z_chunk^T via bf16 MFMA
//     (3-term split, fp32-grade) + partial row sums.
//     Raw-barrier pipeline: global loads stay in flight across barriers
//     (only lgkmcnt drained at the barrier, never vmcnt -> true prefetch).
//     grid = (NCHT, G), block = 256
// ---------------------------------------------------------------------------
template <int NCHT>
__global__ __launch_bounds__(256) void k1_gram(const float* __restrict__ W,
                                               float* __restrict__ psum,
                                               float* __restrict__ prow) {
    constexpr int TD  = D / NCHT;
    constexpr int NST = TD / KSUB;

    __shared__ __align__(16) unsigned short lds_u[3 * PLANE];   // 26112 B

    const int ch   = blockIdx.x;
    const int g    = blockIdx.y;
    const int bid  = g * NCHT + ch;
    const int tid  = threadIdx.x;
    const int lane = tid & 63;
    const int wave = tid >> 6;
    const float* Zg = W + (size_t)g * C * D + (size_t)ch * TD;

    // staging: thread owns row r, 16 cols starting at cb (per subtile)
    const int r  = tid >> 3;            // 0..31
    const int cb = (tid & 7) * 16;      // 0,16,...,112
    const float* srcRow = Zg + (size_t)r * D;

    // compute: fragment geometry for mfma_f32_16x16x32_bf16
    const int lh = lane & 15;
    const int kb = (lane >> 4) * 8;
    const int kbase = wave * 32;

    float4v acc[2][2];
#pragma unroll
    for (int a = 0; a < 2; ++a)
#pragma unroll
        for (int b = 0; b < 2; ++b) acc[a][b] = (float4v)0.f;
    float rs = 0.f;

    float4 cur[4], nxt[4];
#pragma unroll
    for (int i = 0; i < 4; ++i)
        cur[i] = *(const float4*)(srcRow + cb + 4 * i);

#pragma unroll
    for (int st = 0; st < NST; ++st) {
        // issue next-subtile loads; they remain outstanding across the raw
        // barriers below (no vmcnt drain) and are waited only at next split
        if (st + 1 < NST) {
            const float* s = srcRow + (st + 1) * KSUB + cb;
#pragma unroll
            for (int i = 0; i < 4; ++i) nxt[i] = *(const float4*)(s + 4 * i);
        }
        // ---- split cur -> packed bf16 triplets (VALU, overlaps other waves' MFMA) ----
        float x[16];
#pragma unroll
        for (int i = 0; i < 4; ++i) {
            x[4 * i + 0] = cur[i].x; x[4 * i + 1] = cur[i].y;
            x[4 * i + 2] = cur[i].z; x[4 * i + 3] = cur[i].w;
        }
        short8v s1[2], s2[2], s3[2];
#pragma unroll
        for (int q = 0; q < 2; ++q) {
#pragma unroll
            for (int j = 0; j < 8; ++j) {
                unsigned short h1, h2, h3;
                float xv = x[8 * q + j];
                rs += xv;
                split3(xv, h1, h2, h3);
                s1[q][j] = (short)h1; s2[q][j] = (short)h2; s3[q][j] = (short)h3;
            }
        }
        // barrier 1: all waves done reading previous subtile's LDS
        asm volatile("" ::: "memory");
        __builtin_amdgcn_s_barrier();
        asm volatile("" ::: "memory");
        const int widx = r * PSTR + cb;
#pragma unroll
        for (int q = 0; q < 2; ++q) {
            *(short8v*)&lds_u[widx + 8 * q]             = s1[q];
            *(short8v*)&lds_u[PLANE + widx + 8 * q]     = s2[q];
            *(short8v*)&lds_u[2 * PLANE + widx + 8 * q] = s3[q];
        }
        // drain only LDS writes (keep global loads in flight), then barrier 2
        asm volatile("s_waitcnt lgkmcnt(0)" ::: "memory");
        __builtin_amdgcn_s_barrier();
        asm volatile("" ::: "memory");
        // ---- 6 fragment reads, 24 MFMAs ----
        short8v fr[2][3];
#pragma unroll
        for (int h = 0; h < 2; ++h)
#pragma unroll
            for (int p = 0; p < 3; ++p)
                fr[h][p] = *(const short8v*)&lds_u[p * PLANE + (16 * h + lh) * PSTR + kbase + kb];
#pragma unroll
        for (int a = 0; a < 2; ++a)
#pragma unroll
            for (int b = 0; b < 2; ++b) {
                float4v t = acc[a][b];
                t = __builtin_amdgcn_mfma_f32_16x16x32_bf16(fr[a][0], fr[b][0], t, 0, 0, 0);
                t = __builtin_amdgcn_mfma_f32_16x16x32_bf16(fr[a][0], fr[b][1], t, 0, 0, 0);
                t = __builtin_amdgcn_mfma_f32_16x16x32_bf16(fr[a][1], fr[b][0], t, 0, 0, 0);
                t = __builtin_amdgcn_mfma_f32_16x16x32_bf16(fr[a][1], fr[b][1], t, 0, 0, 0);
                t = __builtin_amdgcn_mfma_f32_16x16x32_bf16(fr[a][0], fr[b][2], t, 0, 0, 0);
                t = __builtin_amdgcn_mfma_f32_16x16x32_bf16(fr[a][2], fr[b][0], t, 0, 0, 0);
                acc[a][b] = t;
            }
#pragma unroll
        for (int i = 0; i < 4; ++i) cur[i] = nxt[i];
    }

    // ---- rowsum: 8 consecutive lanes share a row ----
#pragma unroll
    for (int off = 1; off <= 4; off <<= 1) rs += __shfl_xor(rs, off, 64);
    if ((tid & 7) == 0) prow[(size_t)bid * C + r] = rs;

    // ---- cross-wave Gram reduction (reuse LDS as red[4][32][33] f32) ----
    __syncthreads();   // full drain OK here (once per block)
    float* red = (float*)lds_u;
#pragma unroll
    for (int a = 0; a < 2; ++a)
#pragma unroll
        for (int b = 0; b < 2; ++b)
#pragma unroll
            for (int j = 0; j < 4; ++j) {
                int row = 16 * a + ((lane >> 4) << 2) + j;   // m89-verified C/D map
                int col = 16 * b + lh;
                red[wave * 1056 + row * 33 + col] = acc[a][b][j];
            }
    __syncthreads();
#pragma unroll
    for (int k = 0; k < 4; ++k) {
        int el = tid + 256 * k;
        int row = el >> 5, col = el & 31;
        int o = row * 33 + col;
        float sv = red[o] + red[1056 + o] + red[2112 + o] + red[3168 + o];
        psum[(size_t)bid * (C * C) + el] = sv;
    }
}

// ---------------------------------------------------------------------------
// K2: per group: S = sum(partials) - D*m*m^T + EPS*I; Frobenius-normalize;
//     5 Newton-Schulz iterations; emit M^T and v = M*m.
// ---------------------------------------------------------------------------
template <int NCHT>
__global__ __launch_bounds__(256) void k2_ns(const float* __restrict__ psum,
                                             const float* __restrict__ prow,
                                             float* __restrict__ MT,
                                             float* __restrict__ vout) {
    __shared__ float S[C][C + 1];
    __shared__ float B[C][C + 1];
    __shared__ float T1[C][C + 1];
    __shared__ float T2[C][C + 1];
    __shared__ float mean[C];
    __shared__ float redw[4];
    __shared__ float normsh;

    const int g   = blockIdx.x;
    const int tid = threadIdx.x;
    const int e   = tid & 31;
    const int cbq = tid >> 5;

    float selt[4];
#pragma unroll
    for (int k = 0; k < 4; ++k) {
        int el = tid + 256 * k;
        float s = 0.f;
#pragma unroll
        for (int ch = 0; ch < NCHT; ++ch)
            s += psum[((size_t)g * NCHT + ch) * (C * C) + el];
        selt[k] = s;
    }
    if (tid < C) {
        float s = 0.f;
#pragma unroll
        for (int ch = 0; ch < NCHT; ++ch)
            s += prow[((size_t)g * NCHT + ch) * C + tid];
        mean[tid] = s / (float)D;
    }
    __syncthreads();

    float ss = 0.f;
#pragma unroll
    for (int k = 0; k < 4; ++k) {
        int el = tid + 256 * k;
        int c = el >> 5;
        float sv = selt[k] - (float)D * mean[c] * mean[e];
        if (c == e) sv += EPS;
        S[c][e] = sv;
        ss = fmaf(sv, sv, ss);
    }
#pragma unroll
    for (int off = 32; off >= 1; off >>= 1) ss += __shfl_xor(ss, off, 64);
    if ((tid & 63) == 0) redw[tid >> 6] = ss;
    __syncthreads();
    if (tid == 0) normsh = sqrtf(redw[0] + redw[1] + redw[2] + redw[3]);
    __syncthreads();
    const float inv_norm = 1.0f / normsh;
#pragma unroll
    for (int k = 0; k < 4; ++k) {
        int c = cbq + 8 * k;
        S[c][e] *= inv_norm;
        B[c][e] = (c == e) ? 1.f : 0.f;
    }
    __syncthreads();

    for (int it = 0; it < NS_ITERS; ++it) {
#pragma unroll
        for (int k = 0; k < 4; ++k) {
            int c = cbq + 8 * k;
            float s = 0.f;
            for (int kk = 0; kk < C; ++kk)
                s = fmaf(B[c][kk], B[kk][e], s);
            T1[c][e] = s;
        }
        __syncthreads();
#pragma unroll
        for (int k = 0; k < 4; ++k) {
            int c = cbq + 8 * k;
            float s = 0.f;
            for (int kk = 0; kk < C; ++kk)
                s = fmaf(T1[c][kk], B[kk][e], s);
            T2[c][e] = s;
        }
        __syncthreads();
        float pv[4];
#pragma unroll
        for (int k = 0; k < 4; ++k) {
            int c = cbq + 8 * k;
            float s = 0.f;
            for (int kk = 0; kk < C; ++kk)
                s = fmaf(T2[c][kk], S[kk][e], s);
            pv[k] = s;
        }
#pragma unroll
        for (int k = 0; k < 4; ++k) {
            int c = cbq + 8 * k;
            B[c][e] = 1.5f * B[c][e] - 0.5f * pv[k];
        }
        __syncthreads();
    }

    const float invs = 1.0f / sqrtf(normsh);
#pragma unroll
    for (int k = 0; k < 4; ++k) {
        int c = cbq + 8 * k;
        MT[(size_t)g * (C * C) + e * C + c] = B[c][e] * invs;
    }
    if (tid < C) {
        float s = 0.f;
        for (int ee = 0; ee < C; ++ee)
            s = fmaf(B[tid][ee] * invs, mean[ee], s);
        vout[(size_t)g * C + tid] = s;
    }
}

// ---------------------------------------------------------------------------
// K3: W_out = M * Z - v * 1^T, 2 cols/thread (float2), plain stores.
//     grid = (36, 64), block = 256
// ---------------------------------------------------------------------------
__global__ __launch_bounds__(256) void k3_apply(const float* __restrict__ W,
                                                const float* __restrict__ MT,
                                                const float* __restrict__ vv,
                                                float* __restrict__ out) {
    const int g  = blockIdx.y;
    const int d0 = blockIdx.x * 512 + (int)threadIdx.x * 2;
    const float* Zg = W + (size_t)g * C * D + d0;
    const float* Mg = MT + (size_t)g * (C * C);

    float accx[C], accy[C];
#pragma unroll
    for (int r = 0; r < C; ++r) { accx[r] = 0.f; accy[r] = 0.f; }

    for (int e = 0; e < C; ++e) {
        float2 z = *(const float2*)(Zg + (size_t)e * D);
#pragma unroll
        for (int r = 0; r < C; ++r) {
            float m = Mg[e * C + r];   // wave-uniform -> scalar load
            accx[r] = fmaf(m, z.x, accx[r]);
            accy[r] = fmaf(m, z.y, accy[r]);
        }
    }

    float* Og = out + (size_t)g * C * D + d0;
#pragma unroll
    for (int r = 0; r < C; ++r) {
        float vr = vv[g * C + r];      // wave-uniform
        float2 o = make_float2(accx[r] - vr, accy[r] - vr);
        *(float2*)(Og + (size_t)r * D) = o;
    }
}

extern "C" void kernel_launch(void* const* d_in, const int* in_sizes, int n_in,
                              void* d_out, int out_size, void* d_ws, size_t ws_size,
                              hipStream_t stream) {
    const float* w = (const float*)d_in[0];
    float* out = (float*)d_out;

    const size_t need24 = ((size_t)G * 24 * (C * C + C) + (size_t)G * (C * C + C)) * sizeof(float);
    const bool use24 = (ws_size >= need24);
    const int nch = use24 ? 24 : 16;

    float* psum = (float*)d_ws;
    float* prow = psum + (size_t)(G * nch) * (C * C);
    float* MT   = prow + (size_t)(G * nch) * C;
    float* vv   = MT   + (size_t)G * (C * C);

    if (use24) {
        k1_gram<24><<<dim3(24, G), 256, 0, stream>>>(w, psum, prow);
        k2_ns<24>  <<<G,           256, 0, stream>>>(psum, prow, MT, vv);
    } else {
        k1_gram<16><<<dim3(16, G), 256, 0, stream>>>(w, psum, prow);
        k2_ns<16>  <<<G,           256, 0, stream>>>(psum, prow, MT, vv);
    }
    k3_apply<<<dim3(D / 512, G), 256, 0, stream>>>(w, MT, vv, out);
}

// Round 6
// 94.603 us; speedup vs baseline: 1.1076x; 1.0932x over previous
//
#include <hip/hip_runtime.h>

#define G 64
#define C 32
#define D 18432
#define NCH 16          // chunks per group: 1024 blocks = 4/CU exact
#define TD (D / NCH)    // 1152 cols per chunk
#define NST (TD / 128)  // 9 iterations (4 waves x 32 k-cols each)
#define EPS 1e-5f
#define NS_ITERS 5

typedef __attribute__((ext_vector_type(8))) short short8v;
typedef __attribute__((ext_vector_type(4))) float float4v;

__device__ __forceinline__ void split3(float x, unsigned short& h1,
                                       unsigned short& h2, unsigned short& h3) {
    unsigned int u = __float_as_uint(x);
    unsigned int m1 = u & 0xffff0000u;
    float r1 = x - __uint_as_float(m1);
    unsigned int u2 = __float_as_uint(r1);
    unsigned int m2 = u2 & 0xffff0000u;
    float r2 = r1 - __uint_as_float(m2);
    h1 = (unsigned short)(m1 >> 16);
    h2 = (unsigned short)(m2 >> 16);
    h3 = (unsigned short)(__float_as_uint(r2) >> 16);
}

// split 8 fp32 (two float4) into three bf16x8 fragments, accumulate row sum
__device__ __forceinline__ void split8(const float4& v0, const float4& v1,
                                       short8v& p1, short8v& p2, short8v& p3,
                                       float& rs) {
    float x[8] = {v0.x, v0.y, v0.z, v0.w, v1.x, v1.y, v1.z, v1.w};
#pragma unroll
    for (int j = 0; j < 8; ++j) {
        unsigned short h1, h2, h3;
        rs += x[j];
        split3(x[j], h1, h2, h3);
        p1[j] = (short)h1; p2[j] = (short)h2; p3[j] = (short)h3;
    }
}

// ---------------------------------------------------------------------------
// K1: LDS-FREE partial Gram P = Z_chunk * Z_chunk^T via bf16 MFMA (3-term
//     split, fp32-grade). Lane l's MFMA fragment (rows l&15 / +16, k-slice
//     (l>>4)*8) IS a coalesced global load -> no LDS staging, no barriers in
//     the K-loop; loads pipeline freely across iterations via vmcnt.
//     grid = (NCH, G), block = 256 (4 waves, each owns 32 k-cols per iter)
// ---------------------------------------------------------------------------
__global__ __launch_bounds__(256) void k1_gram(const float* __restrict__ W,
                                               float* __restrict__ psum,
                                               float* __restrict__ prow) {
    __shared__ float red[4 * 1056 + 4 * C];   // Gram partials + rowsum partials

    const int ch   = blockIdx.x;
    const int g    = blockIdx.y;
    const int bid  = g * NCH + ch;
    const int tid  = threadIdx.x;
    const int lane = tid & 63;
    const int wave = tid >> 6;

    const int rbase = lane & 15;          // fragment row within 16-half
    const int koff  = (lane >> 4) * 8;    // k-slice within 32-col step

    const float* Zg   = W + (size_t)g * C * D + (size_t)ch * TD;
    const float* p0   = Zg + (size_t)rbase * D + wave * 32 + koff;        // rows 0..15
    const float* p1   = p0 + (size_t)16 * D;                              // rows 16..31

    float4v acc[2][2];
#pragma unroll
    for (int a = 0; a < 2; ++a)
#pragma unroll
        for (int b = 0; b < 2; ++b) acc[a][b] = (float4v)0.f;
    float rs0 = 0.f, rs1 = 0.f;

    float4 c00 = *(const float4*)(p0);
    float4 c01 = *(const float4*)(p0 + 4);
    float4 c10 = *(const float4*)(p1);
    float4 c11 = *(const float4*)(p1 + 4);

#pragma unroll
    for (int st = 0; st < NST; ++st) {
        float4 n00, n01, n10, n11;
        if (st + 1 < NST) {
            n00 = *(const float4*)(p0 + (st + 1) * 128);
            n01 = *(const float4*)(p0 + (st + 1) * 128 + 4);
            n10 = *(const float4*)(p1 + (st + 1) * 128);
            n11 = *(const float4*)(p1 + (st + 1) * 128 + 4);
        }
        short8v fa[3], fb[3];
        split8(c00, c01, fa[0], fa[1], fa[2], rs0);
        split8(c10, c11, fb[0], fb[1], fb[2], rs1);

        short8v* fr[2] = {fa, fb};
#pragma unroll
        for (int a = 0; a < 2; ++a)
#pragma unroll
            for (int b = 0; b < 2; ++b) {
                float4v t = acc[a][b];
                t = __builtin_amdgcn_mfma_f32_16x16x32_bf16(fr[a][0], fr[b][0], t, 0, 0, 0);
                t = __builtin_amdgcn_mfma_f32_16x16x32_bf16(fr[a][0], fr[b][1], t, 0, 0, 0);
                t = __builtin_amdgcn_mfma_f32_16x16x32_bf16(fr[a][1], fr[b][0], t, 0, 0, 0);
                t = __builtin_amdgcn_mfma_f32_16x16x32_bf16(fr[a][1], fr[b][1], t, 0, 0, 0);
                t = __builtin_amdgcn_mfma_f32_16x16x32_bf16(fr[a][0], fr[b][2], t, 0, 0, 0);
                t = __builtin_amdgcn_mfma_f32_16x16x32_bf16(fr[a][2], fr[b][0], t, 0, 0, 0);
                acc[a][b] = t;
            }
        c00 = n00; c01 = n01; c10 = n10; c11 = n11;
    }

    // rowsum: lanes {l, l+16, l+32, l+48} hold partials of the same row
    rs0 += __shfl_xor(rs0, 16, 64); rs0 += __shfl_xor(rs0, 32, 64);
    rs1 += __shfl_xor(rs1, 16, 64); rs1 += __shfl_xor(rs1, 32, 64);
    if (lane < 16) {
        red[4224 + wave * C + lane]      = rs0;
        red[4224 + wave * C + 16 + lane] = rs1;
    }

    // Gram partials -> LDS (m89-verified C/D map: col=lane&15, row=(lane>>4)*4+j)
#pragma unroll
    for (int a = 0; a < 2; ++a)
#pragma unroll
        for (int b = 0; b < 2; ++b)
#pragma unroll
            for (int j = 0; j < 4; ++j) {
                int row = 16 * a + ((lane >> 4) << 2) + j;
                int col = 16 * b + (lane & 15);
                red[wave * 1056 + row * 33 + col] = acc[a][b][j];
            }
    __syncthreads();

#pragma unroll
    for (int k = 0; k < 4; ++k) {
        int el = tid + 256 * k;
        int row = el >> 5, col = el & 31;
        int o = row * 33 + col;
        float sv = red[o] + red[1056 + o] + red[2112 + o] + red[3168 + o];
        psum[(size_t)bid * (C * C) + el] = sv;
    }
    if (tid < C) {
        float s = red[4224 + tid] + red[4224 + C + tid] +
                  red[4224 + 2 * C + tid] + red[4224 + 3 * C + tid];
        prow[(size_t)bid * C + tid] = s;
    }
}

// ---------------------------------------------------------------------------
// K2: per group: S = sum(partials) - D*m*m^T + EPS*I; Frobenius-normalize;
//     5 Newton-Schulz iterations; emit M^T and v = M*m.  (compile-time NCH)
// ---------------------------------------------------------------------------
__global__ __launch_bounds__(256) void k2_ns(const float* __restrict__ psum,
                                             const float* __restrict__ prow,
                                             float* __restrict__ MT,
                                             float* __restrict__ vout) {
    __shared__ float S[C][C + 1];
    __shared__ float B[C][C + 1];
    __shared__ float T1[C][C + 1];
    __shared__ float T2[C][C + 1];
    __shared__ float mean[C];
    __shared__ float redw[4];
    __shared__ float normsh;

    const int g   = blockIdx.x;
    const int tid = threadIdx.x;
    const int e   = tid & 31;
    const int cbq = tid >> 5;

    float selt[4];
#pragma unroll
    for (int k = 0; k < 4; ++k) {
        int el = tid + 256 * k;
        float s = 0.f;
#pragma unroll
        for (int ch = 0; ch < NCH; ++ch)
            s += psum[((size_t)g * NCH + ch) * (C * C) + el];
        selt[k] = s;
    }
    if (tid < C) {
        float s = 0.f;
#pragma unroll
        for (int ch = 0; ch < NCH; ++ch)
            s += prow[((size_t)g * NCH + ch) * C + tid];
        mean[tid] = s / (float)D;
    }
    __syncthreads();

    float ss = 0.f;
#pragma unroll
    for (int k = 0; k < 4; ++k) {
        int el = tid + 256 * k;
        int c = el >> 5;
        float sv = selt[k] - (float)D * mean[c] * mean[e];
        if (c == e) sv += EPS;
        S[c][e] = sv;
        ss = fmaf(sv, sv, ss);
    }
#pragma unroll
    for (int off = 32; off >= 1; off >>= 1) ss += __shfl_xor(ss, off, 64);
    if ((tid & 63) == 0) redw[tid >> 6] = ss;
    __syncthreads();
    if (tid == 0) normsh = sqrtf(redw[0] + redw[1] + redw[2] + redw[3]);
    __syncthreads();
    const float inv_norm = 1.0f / normsh;
#pragma unroll
    for (int k = 0; k < 4; ++k) {
        int c = cbq + 8 * k;
        S[c][e] *= inv_norm;
        B[c][e] = (c == e) ? 1.f : 0.f;
    }
    __syncthreads();

    for (int it = 0; it < NS_ITERS; ++it) {
#pragma unroll
        for (int k = 0; k < 4; ++k) {
            int c = cbq + 8 * k;
            float s = 0.f;
            for (int kk = 0; kk < C; ++kk)
                s = fmaf(B[c][kk], B[kk][e], s);
            T1[c][e] = s;
        }
        __syncthreads();
#pragma unroll
        for (int k = 0; k < 4; ++k) {
            int c = cbq + 8 * k;
            float s = 0.f;
            for (int kk = 0; kk < C; ++kk)
                s = fmaf(T1[c][kk], B[kk][e], s);
            T2[c][e] = s;
        }
        __syncthreads();
        float pv[4];
#pragma unroll
        for (int k = 0; k < 4; ++k) {
            int c = cbq + 8 * k;
            float s = 0.f;
            for (int kk = 0; kk < C; ++kk)
                s = fmaf(T2[c][kk], S[kk][e], s);
            pv[k] = s;
        }
#pragma unroll
        for (int k = 0; k < 4; ++k) {
            int c = cbq + 8 * k;
            B[c][e] = 1.5f * B[c][e] - 0.5f * pv[k];
        }
        __syncthreads();
    }

    const float invs = 1.0f / sqrtf(normsh);
#pragma unroll
    for (int k = 0; k < 4; ++k) {
        int c = cbq + 8 * k;
        MT[(size_t)g * (C * C) + e * C + c] = B[c][e] * invs;
    }
    if (tid < C) {
        float s = 0.f;
        for (int ee = 0; ee < C; ++ee)
            s = fmaf(B[tid][ee] * invs, mean[ee], s);
        vout[(size_t)g * C + tid] = s;
    }
}

// ---------------------------------------------------------------------------
// K3: W_out = M * Z - v * 1^T   (per group), 2 cols per thread (float2)
//     (proven R1/R3 form: flat 1D grid, plain stores)
// ---------------------------------------------------------------------------
__global__ __launch_bounds__(256) void k3_apply(const float* __restrict__ W,
                                                const float* __restrict__ MT,
                                                const float* __restrict__ vv,
                                                float* __restrict__ out) {
    const int blocksPerGroup = D / 512;     // 36
    const int g   = blockIdx.x / blocksPerGroup;
    const int cbk = blockIdx.x % blocksPerGroup;
    const int d0  = cbk * 512 + (int)threadIdx.x * 2;
    const float* Zg = W + (size_t)g * C * D + d0;
    const float* Mg = MT + (size_t)g * (C * C);

    float accx[C], accy[C];
#pragma unroll
    for (int r = 0; r < C; ++r) { accx[r] = 0.f; accy[r] = 0.f; }

    for (int e = 0; e < C; ++e) {
        float2 z = *(const float2*)(Zg + (size_t)e * D);
#pragma unroll
        for (int r = 0; r < C; ++r) {
            float m = Mg[e * C + r];   // wave-uniform -> scalar load
            accx[r] = fmaf(m, z.x, accx[r]);
            accy[r] = fmaf(m, z.y, accy[r]);
        }
    }

    float* Og = out + (size_t)g * C * D + d0;
#pragma unroll
    for (int r = 0; r < C; ++r) {
        float vr = vv[g * C + r];      // wave-uniform
        float2 o = make_float2(accx[r] - vr, accy[r] - vr);
        *(float2*)(Og + (size_t)r * D) = o;
    }
}

extern "C" void kernel_launch(void* const* d_in, const int* in_sizes, int n_in,
                              void* d_out, int out_size, void* d_ws, size_t ws_size,
                              hipStream_t stream) {
    const float* w = (const float*)d_in[0];
    float* out = (float*)d_out;

    float* psum = (float*)d_ws;                          // G*NCH*1024 floats (4.2 MB)
    float* prow = psum + (size_t)(G * NCH) * (C * C);    // G*NCH*32
    float* MT   = prow + (size_t)(G * NCH) * C;          // G*1024
    float* vv   = MT   + (size_t)G * (C * C);            // G*32

    k1_gram<<<dim3(NCH, G), 256, 0, stream>>>(w, psum, prow);
    k2_ns  <<<G,            256, 0, stream>>>(psum, prow, MT, vv);
    k3_apply<<<G * (D / 512), 256, 0, stream>>>(w, MT, vv, out);
}